// Round 1
// baseline (1323.454 us; speedup 1.0000x reference)
//
#include <hip/hip_runtime.h>

#define N_NODES 200000
#define N_EDGES 6400000
#define IN_DIM 15
#define POS_DIM 4

// Pass A: per-node precompute.
// tabI[n] = [a_dst0+p0, a_dst1+p1, p0, p1]      (consumed via edge dst index i)
// tabJ[n] = [a_src0+p0, a_src1+p1, v0-p0, v1-p1] (consumed via edge src index j)
__global__ void node_prep(const float* __restrict__ x,
                          const float* __restrict__ Wlin,
                          const float* __restrict__ Wsrc,
                          const float* __restrict__ Wdst,
                          const float* __restrict__ Wpos,
                          float4* __restrict__ tabI,
                          float4* __restrict__ tabJ)
{
    int n = blockIdx.x * blockDim.x + threadIdx.x;
    if (n >= N_NODES) return;
    const float* xp = x + (long)n * IN_DIM;
    float xv[IN_DIM];
#pragma unroll
    for (int k = 0; k < IN_DIM; ++k) xv[k] = xp[k];

    float p0 = 0.f, p1 = 0.f;
#pragma unroll
    for (int k = 0; k < POS_DIM; ++k) {
        p0 += Wpos[k] * xv[k];
        p1 += Wpos[POS_DIM + k] * xv[k];
    }
    float v0 = 0.f, v1 = 0.f, as0 = 0.f, as1 = 0.f, ad0 = 0.f, ad1 = 0.f;
#pragma unroll
    for (int k = 0; k < IN_DIM; ++k) {
        float xk = xv[k];
        v0  += Wlin[k] * xk;           v1  += Wlin[IN_DIM + k] * xk;
        as0 += Wsrc[k] * xk;           as1 += Wsrc[IN_DIM + k] * xk;
        ad0 += Wdst[k] * xk;           ad1 += Wdst[IN_DIM + k] * xk;
    }
    tabI[n] = make_float4(ad0 + p0, ad1 + p1, p0, p1);
    tabJ[n] = make_float4(as0 + p0, as1 + p1, v0 - p0, v1 - p1);
}

// Pass B: single fused edge pass. alpha = tabI[i].xy - tabJ[j].xy + b
// e = exp(alpha)  (no max-subtraction: softmax shift-invariant, |alpha| <~ 6)
// den[i] += e ;  num[i] += e * (tabJ[j].zw + tabI[i].zw + b)
__global__ void edge_pass(const int* __restrict__ idx,
                          const float4* __restrict__ tabI,
                          const float4* __restrict__ tabJ,
                          const float* __restrict__ bpos,
                          float* __restrict__ num0, float* __restrict__ num1,
                          float* __restrict__ den0, float* __restrict__ den1)
{
    int e = blockIdx.x * blockDim.x + threadIdx.x;
    if (e >= N_EDGES) return;
    int i = idx[e];
    int j = idx[N_EDGES + e];
    float4 fi = tabI[i];
    float4 fj = tabJ[j];
    float b0 = bpos[0], b1 = bpos[1];
    float a0 = fi.x - fj.x + b0;
    float a1 = fi.y - fj.y + b1;
    float e0 = __expf(a0);
    float e1 = __expf(a1);
    atomicAdd(&den0[i], e0);
    atomicAdd(&den1[i], e1);
    atomicAdd(&num0[i], e0 * (fj.z + fi.z + b0));
    atomicAdd(&num1[i], e1 * (fj.w + fi.w + b1));
}

// Pass C: out[n][c] = num_c[n] / (den_c[n] + 1e-16)
__global__ void finalize(const float* __restrict__ num0,
                         const float* __restrict__ num1,
                         const float* __restrict__ den0,
                         const float* __restrict__ den1,
                         float* __restrict__ out)
{
    int n = blockIdx.x * blockDim.x + threadIdx.x;
    if (n >= N_NODES) return;
    float o0 = num0[n] / (den0[n] + 1e-16f);
    float o1 = num1[n] / (den1[n] + 1e-16f);
    out[2 * n]     = o0;
    out[2 * n + 1] = o1;
}

extern "C" void kernel_launch(void* const* d_in, const int* in_sizes, int n_in,
                              void* d_out, int out_size, void* d_ws, size_t ws_size,
                              hipStream_t stream) {
    const float* x    = (const float*)d_in[0];
    const int*   idx  = (const int*)d_in[1];   // edge_index flat (2, E): [0..E)=i, [E..2E)=j
    const float* Wlin = (const float*)d_in[2];
    const float* Wsrc = (const float*)d_in[3];
    const float* Wdst = (const float*)d_in[4];
    const float* Wpos = (const float*)d_in[5];
    const float* bpos = (const float*)d_in[6];
    float* out = (float*)d_out;

    char* ws = (char*)d_ws;
    float4* tabI = (float4*)ws;                                   // 3.2 MB
    float4* tabJ = (float4*)(ws + (size_t)N_NODES * 16);          // 3.2 MB
    float*  acc  = (float*)(ws + (size_t)2 * N_NODES * 16);       // 4 x 0.8 MB
    float* num0 = acc;
    float* num1 = acc + N_NODES;
    float* den0 = acc + 2 * N_NODES;
    float* den1 = acc + 3 * N_NODES;

    // accumulators must be zeroed every launch (ws is re-poisoned to 0xAA)
    hipMemsetAsync(acc, 0, (size_t)4 * N_NODES * sizeof(float), stream);

    node_prep<<<(N_NODES + 255) / 256, 256, 0, stream>>>(x, Wlin, Wsrc, Wdst, Wpos, tabI, tabJ);
    edge_pass<<<(N_EDGES + 255) / 256, 256, 0, stream>>>(idx, tabI, tabJ, bpos,
                                                         num0, num1, den0, den1);
    finalize<<<(N_NODES + 255) / 256, 256, 0, stream>>>(num0, num1, den0, den1, out);
}